// Round 9
// baseline (296.363 us; speedup 1.0000x reference)
//
#include <hip/hip_runtime.h>
#include <hip/hip_bf16.h>

// Non-local attention block, B=8 C=256 C2=128 H=W=64 (HW=4096), pooled 32x32 (1024).
// Round 9: attention reads K/V fragments DIRECTLY from global (L2-resident, 256KB each per
// batch) — no kT/vT LDS staging, no barriers in the K-loop, LDS = per-wave pS only (8KB).
// Everything else identical to passing round-8 kernel.
//
// Pipeline:
//   T1:      a (f32 NCHW) -> aTg bf16 [b][px][c]          (LDS transpose)
//   conv12m: MFMA GEMM -> y1 bf16 NCHW [b][c2][hw], y2 bf16 NCHW [b][c2][hw]
//   pool:    y2 -> pT [b][pos][chan], x3T [b][j][k]  (raw-view transposes for attention)
//   attn:    flash MFMA on raw views; O rows written flat over y1 (== o4 NCHW flat)
//   T2:      y1 (o4 NCHW [c2][hw]) -> x4T bf16 [b][hw][c2]
//   conv3m:  MFMA GEMM + BN + ReLU + residual -> out f32 NCHW
//
// d_out scratch (u16 idx, cap 16,777,216): aTg @0 (8.4M, dead after conv12; pool then
//   reuses @0 for pT (1M) and @1M for x3T (1M)), y2 @8,388,608 (4.2M), y1 @12,582,912 (4.2M).
// ws: x4T @0 (4.2M u16 = 8 MB).

typedef unsigned short u16;
typedef unsigned int u32;
typedef short  bf16x8 __attribute__((ext_vector_type(8)));
typedef float  f32x4  __attribute__((ext_vector_type(4)));

#define DEV static __device__ __forceinline__

DEV float bf2f(u16 v){ return __uint_as_float(((u32)v)<<16); }
DEV float bflo(u32 p){ return __uint_as_float(p<<16); }
DEV float bfhi(u32 p){ return __uint_as_float(p & 0xFFFF0000u); }
DEV u16 f2bf(float f){
  u32 x = __float_as_uint(f);
  x += 0x7FFFu + ((x>>16)&1u);   // RNE
  return (u16)(x>>16);
}
DEV u32 pack2(float a, float b){ return ((u32)f2bf(a)) | (((u32)f2bf(b))<<16); }

// ---------------- T1: a f32 NCHW [256][4096] -> aTg bf16 [4096 px][256 c] ----------------
__global__ __launch_bounds__(256) void k_t1(const float* __restrict__ a, u16* __restrict__ aTg){
  __shared__ u16 L[64*72];                      // 64 hw x 64 c tile, row pad 72
  const int t = threadIdx.x;
  const int hw0 = blockIdx.x*64, c0 = blockIdx.y*64, b = blockIdx.z;
  const float* ab = a + b*1048576;
  #pragma unroll
  for(int it=0; it<4; ++it){
    int c = it*16 + (t>>4);
    int hw = (t&15)*4;
    float4 f = *(const float4*)&ab[(c0+c)*4096 + hw0 + hw];
    L[(hw+0)*72 + c] = f2bf(f.x);
    L[(hw+1)*72 + c] = f2bf(f.y);
    L[(hw+2)*72 + c] = f2bf(f.z);
    L[(hw+3)*72 + c] = f2bf(f.w);
  }
  __syncthreads();
  u16* ob = aTg + b*1048576;
  #pragma unroll
  for(int it=0; it<2; ++it){
    int g2 = it*256 + t;
    int hw = g2>>3, k = g2&7;
    *(uint4*)&ob[(hw0+hw)*256 + c0 + k*8] = *(const uint4*)&L[hw*72 + k*8];
  }
}

// ---------------- T2: y1 (o4 NCHW [128 c2][4096 hw]) -> x4T [hw][c2] --------------------
__global__ __launch_bounds__(256) void k_t2(const u16* __restrict__ y1, u16* __restrict__ x4T){
  __shared__ u16 L[64*72];
  const int t = threadIdx.x;
  const int hw0 = blockIdx.x*64, c20 = blockIdx.y*64, b = blockIdx.z;
  const u16* yb = y1 + b*524288;
  #pragma unroll
  for(int it=0; it<2; ++it){
    int c2 = it*32 + (t>>3);
    int hw = (t&7)*8;
    uint4 d = *(const uint4*)&yb[(c20+c2)*4096 + hw0 + hw];
    const u16* dv = (const u16*)&d;
    #pragma unroll
    for(int j=0;j<8;j++) L[(hw+j)*72 + c2] = dv[j];
  }
  __syncthreads();
  u16* ob = x4T + b*524288;
  #pragma unroll
  for(int it=0; it<2; ++it){
    int g2 = it*256 + t;
    int hw = g2>>3, k = g2&7;
    *(uint4*)&ob[(hw0+hw)*128 + c20 + k*8] = *(const uint4*)&L[hw*72 + k*8];
  }
}

// ---------------- conv12 MFMA: y[oc][px] = relu(BN(aT @ W^T)), NCHW stores -------------------
__global__ __launch_bounds__(512) void k_conv12m(
    const u16* __restrict__ aTg, const float* __restrict__ w1, const float* __restrict__ w2,
    const float* __restrict__ b1, const float* __restrict__ g1, const float* __restrict__ be1,
    const float* __restrict__ m1, const float* __restrict__ v1,
    const float* __restrict__ b2, const float* __restrict__ g2, const float* __restrict__ be2,
    const float* __restrict__ m2, const float* __restrict__ v2,
    u16* __restrict__ y1, u16* __restrict__ y2)
{
  __shared__ __align__(16) u16 aL[128*64];   // [px][64c], 128B rows, unit swz ^(px&7)
  __shared__ __align__(16) u16 wL[256*64];   // [oc][64c]
  __shared__ float scL[256], shL[256];
  const int tid = threadIdx.x;
  const int wv = tid>>6, l = tid&63, g = l>>4, q = l&15;
  const int wpx = wv>>2, woc = wv&3;
  const int px0 = blockIdx.x*128, b = blockIdx.y;

  if (tid < 256){
    int oc = tid, cv = oc>>7, j = oc&127;
    float bias = cv? b2[j] : b1[j];
    float gg   = cv? g2[j] : g1[j];
    float be   = cv? be2[j]: be1[j];
    float mm   = cv? m2[j] : m1[j];
    float vv   = cv? v2[j] : v1[j];
    float sc = gg / sqrtf(vv + 1e-5f);
    scL[oc] = sc;
    shL[oc] = (bias - mm)*sc + be;
  }

  const u16* aTb = aTg + b*1048576;
  const int spx = tid>>2, su = (tid&3)*2;
  uint4 areg[2]; float4 wreg[8];
  {
    areg[0] = *(const uint4*)&aTb[(px0+spx)*256 + 0*64 + su*8];
    areg[1] = *(const uint4*)&aTb[(px0+spx)*256 + 0*64 + (su+1)*8];
    #pragma unroll
    for(int it=0; it<8; ++it){
      int ocr = it*32 + (tid>>4); int fu = tid&15;
      const float* wp = (it<4)? &w1[ocr*256] : &w2[(ocr-128)*256];
      wreg[it] = *(const float4*)&wp[0*64 + fu*4];
    }
  }

  f32x4 acc[4][4];
  #pragma unroll
  for(int m=0;m<4;m++){
    #pragma unroll
    for(int n=0;n<4;n++) acc[m][n] = (f32x4){0.f,0.f,0.f,0.f};
  }

  for(int kc=0; kc<4; ++kc){
    __syncthreads();
    *(uint4*)((char*)aL + spx*128 + (( su   ^(spx&7))<<4)) = areg[0];
    *(uint4*)((char*)aL + spx*128 + (((su+1)^(spx&7))<<4)) = areg[1];
    #pragma unroll
    for(int it=0; it<8; ++it){
      int ocr = it*32 + (tid>>4), fu = tid&15, u = fu>>1, h = fu&1;
      *(uint2*)((char*)wL + ocr*128 + ((u^(ocr&7))<<4) + h*8)
          = make_uint2(pack2(wreg[it].x, wreg[it].y), pack2(wreg[it].z, wreg[it].w));
    }
    __syncthreads();
    if (kc<3){
      areg[0] = *(const uint4*)&aTb[(px0+spx)*256 + (kc+1)*64 + su*8];
      areg[1] = *(const uint4*)&aTb[(px0+spx)*256 + (kc+1)*64 + (su+1)*8];
      #pragma unroll
      for(int it=0; it<8; ++it){
        int ocr = it*32 + (tid>>4); int fu = tid&15;
        const float* wp = (it<4)? &w1[ocr*256] : &w2[(ocr-128)*256];
        wreg[it] = *(const float4*)&wp[(kc+1)*64 + fu*4];
      }
    }
    #pragma unroll
    for(int ks=0; ks<2; ++ks){
      bf16x8 Af[4], Bf[4];
      #pragma unroll
      for(int n=0;n<4;n++)
        Af[n] = *(const bf16x8*)((char*)wL + (woc*64+n*16+q)*128 + (((ks*4+g)^(q&7))<<4));
      #pragma unroll
      for(int m=0;m<4;m++)
        Bf[m] = *(const bf16x8*)((char*)aL + (wpx*64+m*16+q)*128 + (((ks*4+g)^(q&7))<<4));
      #pragma unroll
      for(int m=0;m<4;m++){
        #pragma unroll
        for(int n=0;n<4;n++)
          acc[m][n] = __builtin_amdgcn_mfma_f32_16x16x32_bf16(Af[n], Bf[m], acc[m][n], 0,0,0);
      }
    }
  }

  // Epilogue: BOTH convs store NCHW [c][4096]+px (raw-reshape semantics depend on this!)
  u16* yb   = (woc < 2) ? (y1 + b*524288) : (y2 + b*524288);
  const int coff = (woc < 2) ? 0 : 128;
  #pragma unroll
  for(int m=0;m<4;m++){
    int px = px0 + wpx*64 + m*16 + q;
    #pragma unroll
    for(int n=0;n<4;n++){
      #pragma unroll
      for(int e=0;e<4;e++){
        int oc = woc*64 + n*16 + g*4 + e;
        yb[(oc - coff)*4096 + px] = f2bf(fmaxf(acc[m][n][e]*scL[oc] + shL[oc], 0.f));
      }
    }
  }
}

// ---------------- pool: maxpool 3x3 s2 p1 on y2 NCHW -> pT [pos][chan], x3T [j][k] -----------
__global__ __launch_bounds__(256) void k_pool(const u16* __restrict__ y2,
                                              u16* __restrict__ pTg, u16* __restrict__ x3Tg){
  int idx = blockIdx.x*256 + threadIdx.x;
  int b = idx>>17, rem = idx & 131071;
  int c = rem>>10, pos = rem&1023;
  int oh = pos>>5, ow = pos&31;
  const u16* base = y2 + b*524288 + c*4096;
  float mx = -1e30f;
  #pragma unroll
  for(int dh=-1; dh<=1; ++dh){
    int ih = 2*oh+dh;
    if ((unsigned)ih < 64u){
      #pragma unroll
      for(int dw=-1; dw<=1; ++dw){
        int iw = 2*ow+dw;
        if((unsigned)iw<64u) mx = fmaxf(mx, bf2f(base[ih*64+iw]));
      }
    }
  }
  u16 v = f2bf(mx);
  pTg[b*131072 + pos*128 + c] = v;               // X2^T: [pos][chan]
  int f = c*1024 + pos;                          // raw flat idx of p
  x3Tg[b*131072 + (f&127)*1024 + (f>>7)] = v;    // X3^T: [j][k], X3[k][j]=p_flat[k*128+j]
}

// ---------------- attention: direct-from-L2 fragments, no K/V LDS, no loop barriers ----------
// Block: 64 q-rows, 4 waves x 16 rows. 16 kv-chunks of 64. S^T = mfma(K_frag, Q_frag).
// Fragment byte-identity with round-8 LDS path verified: chunk (kk*4+g) of each row.
__global__ __launch_bounds__(256) void k_attn_mfma(u16* __restrict__ y1,
    const u16* __restrict__ pTg, const u16* __restrict__ x3Tg)
{
  __shared__ __align__(16) u16 pS[4][1024];  // per-wave P staging only (8KB)

  const int tid = threadIdx.x, w = tid>>6, l = tid&63;
  const int g = l>>4, q = l&15;
  const int b = blockIdx.y;
  const int R0 = blockIdx.x*64;
  u16* y1b = y1 + b*524288;
  const u16* pTb = pTg + b*131072;
  const u16* vTb = x3Tg + b*131072;

  // Q fragments direct from global (wave's 16 rows; lane reads its own 16B)
  bf16x8 qf[4];
  #pragma unroll
  for (int kk=0; kk<4; ++kk)
    qf[kk] = *(const bf16x8*)&y1b[(R0 + w*16 + q)*128 + (kk*4+g)*8];

  f32x4 O[8];
  #pragma unroll
  for (int t=0;t<8;t++) O[t] = (f32x4){0.f,0.f,0.f,0.f};
  float m = -3.0e38f, s = 0.f;

  for (int ch=0; ch<16; ++ch){
    const int kv0 = ch*64;

    // S^T: 4 kv-tiles x K=128; K fragments direct from pT (L2-resident)
    f32x4 st[4];
    #pragma unroll
    for (int n=0;n<4;n++) st[n] = (f32x4){0.f,0.f,0.f,0.f};
    #pragma unroll
    for (int kk=0; kk<4; ++kk){
      bf16x8 kf[4];
      #pragma unroll
      for (int n=0;n<4;n++)
        kf[n] = *(const bf16x8*)&pTb[(kv0 + n*16 + q)*128 + (kk*4+g)*8];
      #pragma unroll
      for (int n=0;n<4;n++)
        st[n] = __builtin_amdgcn_mfma_f32_16x16x32_bf16(kf[n], qf[kk], st[n], 0,0,0);
    }

    // online softmax for lane's q-row (row spread over lanes q, q+16, q+32, q+48)
    float cmax = st[0][0];
    #pragma unroll
    for(int n=0;n<4;n++){
      #pragma unroll
      for(int e=0;e<4;e++) cmax = fmaxf(cmax, st[n][e]);
    }
    cmax = fmaxf(cmax, __shfl_xor(cmax,16,64));
    cmax = fmaxf(cmax, __shfl_xor(cmax,32,64));
    float mnew = fmaxf(m, cmax);
    float corr = __expf(m - mnew);
    m = mnew;
    float psum = 0.f;
    #pragma unroll
    for(int n=0;n<4;n++){
      #pragma unroll
      for(int e=0;e<4;e++){ float t_ = __expf(st[n][e]-m); st[n][e]=t_; psum += t_; }
    }
    psum += __shfl_xor(psum,16,64);
    psum += __shfl_xor(psum,32,64);
    s = s*corr + psum;

    // rescale O (O rows q' = g*4+e; corr lives in lane q')
    float cO[4];
    #pragma unroll
    for(int e=0;e<4;e++) cO[e] = __shfl(corr, g*4+e, 64);
    #pragma unroll
    for(int t=0;t<8;t++){
      #pragma unroll
      for(int e=0;e<4;e++) O[t][e] *= cO[e];
    }

    // P -> per-wave LDS (row q, kv consecutive), swizzled 8B units (no barrier needed)
    u16* pSw = pS[w];
    #pragma unroll
    for(int n=0;n<4;n++){
      u32 lo = pack2(st[n][0], st[n][1]);
      u32 hi = pack2(st[n][2], st[n][3]);
      *(uint2*)((char*)pSw + q*128 + (((n*4+g) ^ q)<<3)) = make_uint2(lo,hi);
    }

    // PV: O[q][chan] += P[q][kv] * X3[kv][chan]; V fragments direct from x3T (L2-resident)
    #pragma unroll
    for(int kk2=0; kk2<2; ++kk2){
      int kv4a = kk2*8 + g*2;
      uint2 A0 = *(const uint2*)((char*)pS[w] + q*128 + (((kv4a  ) ^ q)<<3));
      uint2 A1 = *(const uint2*)((char*)pS[w] + q*128 + (((kv4a+1) ^ q)<<3));
      uint4 pa4 = make_uint4(A0.x, A0.y, A1.x, A1.y);
      bf16x8 pf = *(bf16x8*)&pa4;
      #pragma unroll
      for(int t=0;t<8;t++){
        bf16x8 vf = *(const bf16x8*)&vTb[(t*16 + q)*1024 + kv0 + (kk2*4+g)*8];
        O[t] = __builtin_amdgcn_mfma_f32_16x16x32_bf16(pf, vf, O[t], 0,0,0);
      }
    }
  }

  // epilogue: divide by s, write O rows back over y1 (only this block's rows)
  float si[4];
  #pragma unroll
  for(int e=0;e<4;e++) si[e] = 1.0f / __shfl(s, g*4+e, 64);
  u16* ob = y1b + R0*128;
  #pragma unroll
  for(int t=0;t<8;t++){
    #pragma unroll
    for(int e=0;e<4;e++){
      int grow = w*16 + g*4 + e;
      ob[grow*128 + t*16 + q] = f2bf(O[t][e]*si[e]);
    }
  }
}

// ---------------- conv3 MFMA + BN + ReLU + residual -> out f32 NCHW --------------------------
__global__ __launch_bounds__(512) void k_conv3m(
    const u16* __restrict__ x4T, const float* __restrict__ w3,
    const float* __restrict__ b3, const float* __restrict__ g3, const float* __restrict__ be3,
    const float* __restrict__ m3, const float* __restrict__ v3,
    const float* __restrict__ a,  float* __restrict__ out)
{
  __shared__ __align__(16) u16 xL[128*64];
  __shared__ __align__(16) u16 wL[256*64];
  __shared__ float scL[256], shL[256];
  const int tid = threadIdx.x;
  const int wv = tid>>6, l = tid&63, g = l>>4, q = l&15;
  const int wpx = wv>>2, woc = wv&3;
  const int hw0 = blockIdx.x*128, b = blockIdx.y;

  if (tid < 256){
    int oc = tid;
    float sc = g3[oc] / sqrtf(v3[oc] + 1e-5f);
    scL[oc] = sc;
    shL[oc] = (b3[oc] - m3[oc])*sc + be3[oc];
  }

  const u16* xb = x4T + b*524288;
  const int shw = tid>>2, su = (tid&3)*2;
  uint4 xreg[2]; float4 wreg[8];
  {
    xreg[0] = *(const uint4*)&xb[(hw0+shw)*128 + 0*64 + su*8];
    xreg[1] = *(const uint4*)&xb[(hw0+shw)*128 + 0*64 + (su+1)*8];
    #pragma unroll
    for(int it=0; it<8; ++it){
      int ocr = it*32 + (tid>>4); int fu = tid&15;
      wreg[it] = *(const float4*)&w3[ocr*128 + 0*64 + fu*4];
    }
  }

  f32x4 acc[4][4];
  #pragma unroll
  for(int m=0;m<4;m++){
    #pragma unroll
    for(int n=0;n<4;n++) acc[m][n] = (f32x4){0.f,0.f,0.f,0.f};
  }

  for(int kc=0; kc<2; ++kc){
    __syncthreads();
    *(uint4*)((char*)xL + shw*128 + (( su   ^(shw&7))<<4)) = xreg[0];
    *(uint4*)((char*)xL + shw*128 + (((su+1)^(shw&7))<<4)) = xreg[1];
    #pragma unroll
    for(int it=0; it<8; ++it){
      int ocr = it*32 + (tid>>4), fu = tid&15, u = fu>>1, h = fu&1;
      *(uint2*)((char*)wL + ocr*128 + ((u^(ocr&7))<<4) + h*8)
          = make_uint2(pack2(wreg[it].x, wreg[it].y), pack2(wreg[it].z, wreg[it].w));
    }
    __syncthreads();
    if (kc<1){
      xreg[0] = *(const uint4*)&xb[(hw0+shw)*128 + 64 + su*8];
      xreg[1] = *(const uint4*)&xb[(hw0+shw)*128 + 64 + (su+1)*8];
      #pragma unroll
      for(int it=0; it<8; ++it){
        int ocr = it*32 + (tid>>4); int fu = tid&15;
        wreg[it] = *(const float4*)&w3[ocr*128 + 64 + fu*4];
      }
    }
    #pragma unroll
    for(int ks=0; ks<2; ++ks){
      bf16x8 Af[4], Bf[4];
      #pragma unroll
      for(int n=0;n<4;n++)
        Af[n] = *(const bf16x8*)((char*)wL + (woc*64+n*16+q)*128 + (((ks*4+g)^(q&7))<<4));
      #pragma unroll
      for(int m=0;m<4;m++)
        Bf[m] = *(const bf16x8*)((char*)xL + (wpx*64+m*16+q)*128 + (((ks*4+g)^(q&7))<<4));
      #pragma unroll
      for(int m=0;m<4;m++){
        #pragma unroll
        for(int n=0;n<4;n++)
          acc[m][n] = __builtin_amdgcn_mfma_f32_16x16x32_bf16(Af[n], Bf[m], acc[m][n], 0,0,0);
      }
    }
  }

  const float* ab = a + b*1048576;
  float* ob = out + b*1048576;
  #pragma unroll
  for(int m=0;m<4;m++){
    int hw = hw0 + wpx*64 + m*16 + q;
    #pragma unroll
    for(int n=0;n<4;n++){
      #pragma unroll
      for(int e=0;e<4;e++){
        int oc = woc*64 + n*16 + g*4 + e;
        int gi = oc*4096 + hw;
        ob[gi] = fmaxf(acc[m][n][e]*scL[oc] + shL[oc], 0.f) + ab[gi];
      }
    }
  }
}

extern "C" void kernel_launch(void* const* d_in, const int* in_sizes, int n_in,
                              void* d_out, int out_size, void* d_ws, size_t ws_size,
                              hipStream_t stream)
{
  const float* a   = (const float*)d_in[0];
  const float* w1  = (const float*)d_in[1];
  const float* b1  = (const float*)d_in[2];
  const float* g1  = (const float*)d_in[3];
  const float* be1 = (const float*)d_in[4];
  const float* m1  = (const float*)d_in[5];
  const float* v1  = (const float*)d_in[6];
  const float* w2  = (const float*)d_in[7];
  const float* b2  = (const float*)d_in[8];
  const float* g2  = (const float*)d_in[9];
  const float* be2 = (const float*)d_in[10];
  const float* m2  = (const float*)d_in[11];
  const float* v2  = (const float*)d_in[12];
  const float* w3  = (const float*)d_in[13];
  const float* b3  = (const float*)d_in[14];
  const float* g3  = (const float*)d_in[15];
  const float* be3 = (const float*)d_in[16];
  const float* m3  = (const float*)d_in[17];
  const float* v3  = (const float*)d_in[18];
  float* out = (float*)d_out;

  u16* d16  = (u16*)d_out;
  u16* aTg  = d16;                      // 8,388,608 u16 (dead after conv12m)
  u16* pT   = d16;                      // 1,048,576 u16 (reuses aTg space, after conv12m)
  u16* x3T  = d16 + 1048576;            // 1,048,576 u16
  u16* y2   = d16 + 8388608;            // 4,194,304 u16 (dead after pool)
  u16* y1   = d16 + 12582912;           // 4,194,304 u16 (dead after T2)
  u16* x4T  = (u16*)d_ws;               // 4,194,304 u16 (8 MB)

  k_t1      <<<dim3(64,4,8), 256, 0, stream>>>(a, aTg);
  k_conv12m <<<dim3(32,8),   512, 0, stream>>>(aTg,w1,w2,b1,g1,be1,m1,v1,b2,g2,be2,m2,v2,y1,y2);
  k_pool    <<<dim3(4096),   256, 0, stream>>>(y2, pT, x3T);
  k_attn_mfma<<<dim3(64,8),  256, 0, stream>>>(y1, pT, x3T);
  k_t2      <<<dim3(64,2,8), 256, 0, stream>>>(y1, x4T);
  k_conv3m  <<<dim3(32,8),   512, 0, stream>>>(x4T,w3,b3,g3,be3,m3,v3,a,out);
}